// Round 9
// baseline (554.960 us; speedup 1.0000x reference)
//
#include <hip/hip_runtime.h>
#include <hip/hip_bf16.h>

#define BB 1024

typedef __attribute__((ext_vector_type(8))) short bf16x8;   // 8 bf16 = 4 VGPRs
typedef __attribute__((ext_vector_type(4))) float f32x4;    // MFMA C/D

__device__ __forceinline__ float bf2f(unsigned int u) {
    union { unsigned int i; float f; } v; v.i = u << 16; return v.f;
}
__device__ __forceinline__ float bflo(unsigned int w) {
    union { unsigned int i; float f; } v; v.i = w << 16; return v.f;
}
__device__ __forceinline__ float bfhi(unsigned int w) {
    union { unsigned int i; float f; } v; v.i = w & 0xffff0000u; return v.f;
}
__device__ __forceinline__ unsigned short f2bf(float f) {
    union { float f; unsigned int i; } v; v.f = f;
    return (unsigned short)((v.i + 0x7fffu + ((v.i >> 16) & 1u)) >> 16);
}

// all-lane sum over lane-bit4 and lane-bit5 (the 4 g-groups), pure VALU:
// v_permlane16_swap + v_permlane32_swap (both gfx950).
__device__ __forceinline__ float gsum(float x) {
    float a0 = x, a1 = x;
    asm("v_permlane16_swap_b32 %0, %1" : "+v"(a0), "+v"(a1));
    float s = a0 + a1;
    float b0 = s, b1 = s;
    asm("v_permlane32_swap_b32 %0, %1" : "+v"(b0), "+v"(b1));
    return b0 + b1;
}

// ---------------------------------------------------------------------------
// prep: blocks 0..63: VtB[k][d][c] = bf16(Vt[k][c][d]); the 16B c-blocks of
//       each 256B d-row are XOR-swizzled (blk ^= d&15) so linear
//       global_load_lds staging + swizzled ds_read_b128 is conflict-free.
//       block 64: WT[k][c] = bf16(W[c][k]).
// ---------------------------------------------------------------------------
__global__ __launch_bounds__(256) void prep_kernel(
    const float* __restrict__ Vt, const float* __restrict__ W,
    char* __restrict__ VtB, unsigned short* __restrict__ WT)
{
    const int t = threadIdx.x;
    const int blk = blockIdx.x;
    if (blk < 64) {
        __shared__ float tile[64][132];
        const float* src = Vt + (size_t)blk * 16384;
        for (int h = 0; h < 2; ++h) {          // c-halves
            __syncthreads();
            for (int i = 0; i < 8; ++i) {      // stage 64c x 128d floats
                int f4 = t + i * 256;
                int cl = f4 >> 5;              // 0..63
                int d4 = (f4 & 31) << 2;
                const float* s4 = src + (size_t)(h * 64 + cl) * 128 + d4;
                float4 v = *(const float4*)s4;
                tile[cl][d4] = v.x; tile[cl][d4 + 1] = v.y;
                tile[cl][d4 + 2] = v.z; tile[cl][d4 + 3] = v.w;
            }
            __syncthreads();
            int d = t >> 1, ch = t & 1;
            for (int cb = h * 8 + ch * 4; cb < h * 8 + ch * 4 + 4; ++cb) {
                int cbl = cb - h * 8;
                unsigned int w[4];
                #pragma unroll
                for (int j = 0; j < 4; ++j) {
                    unsigned int lo = f2bf(tile[cbl * 8 + 2 * j][d]);
                    unsigned int hi = f2bf(tile[cbl * 8 + 2 * j + 1][d]);
                    w[j] = lo | (hi << 16);
                }
                int oblk = cb ^ (d & 15);
                *(uint4*)(VtB + (size_t)blk * 32768 + d * 256 + oblk * 16) =
                    make_uint4(w[0], w[1], w[2], w[3]);
            }
        }
    } else {
        for (int i = 0; i < 32; ++i) {
            int idx = t * 32 + i;
            int k = idx >> 7, c = idx & 127;
            WT[idx] = f2bf(W[c * 64 + k]);
        }
    }
}

// ---------------------------------------------------------------------------
// leaf gather -> bf16 node rows
// ---------------------------------------------------------------------------
__global__ __launch_bounds__(256) void gather_kernel(
    const int* __restrict__ ids, const float* __restrict__ embed,
    unsigned short* __restrict__ nodes)
{
    int e = blockIdx.x * 256 + threadIdx.x;  // 16B chunk, 8 per row
    int row = e >> 3;
    int part = e & 7;
    int id = ids[row];
    const float* src = embed + (size_t)id * 64 + part * 8;
    float4 a = *(const float4*)src;
    float4 b = *(const float4*)(src + 4);
    unsigned int w0 = (unsigned int)f2bf(a.x) | ((unsigned int)f2bf(a.y) << 16);
    unsigned int w1 = (unsigned int)f2bf(a.z) | ((unsigned int)f2bf(a.w) << 16);
    unsigned int w2 = (unsigned int)f2bf(b.x) | ((unsigned int)f2bf(b.y) << 16);
    unsigned int w3 = (unsigned int)f2bf(b.z) | ((unsigned int)f2bf(b.w) << 16);
    *(uint4*)(nodes + (size_t)row * 64 + part * 8) = make_uint4(w0, w1, w2, w3);
}

// ---------------------------------------------------------------------------
// One tree level. 512 thr = 8 waves; wave w owns the d-EIGHTH
// d = w*16 + (0..15). 64 nodes x KG k per block. Each wave stages its own
// 4KB Vt slice into a PRIVATE 8KB LDS double-buffer (global_load_lds) and
// reads ONLY its own staging -> per-wave vmcnt(0) rotation, ZERO barriers
// in the k-loop (waves self-pace; MFMA of one wave hides loads of another).
// Per k per wave: 4 swizzled ds_read_b128 + 16 MFMA C(d,n)=Vt[k](d,c).x(n,c)^T
// + in-lane 4-d contraction (f32 x-values) + pure-VALU g-reduce
// (permlane16_swap + permlane32_swap); lane g keeps k = k0+g*4+slot.
// Wx: wave 0, one MFMA pass with WT rows (C rows = k-local match yreg).
// Final: barrier, 8-way d-combine via aliased LDS Y, +bias, tanh, store.
// ---------------------------------------------------------------------------
template<int KG>
__global__ __launch_bounds__(512, 4) void bil_kernel(
    unsigned short* __restrict__ nodes, const char* __restrict__ VtB,
    const unsigned short* __restrict__ WT, const float* __restrict__ bias,
    long prev_off, long out_off)
{
    extern __shared__ char smem[];           // 65536: 8 waves x 8KB private dbuf
    float* Y = (float*)smem;                 // post-loop alias: [8][64][20] = 40960B

    const int t    = threadIdx.x;
    const int wave = t >> 6;
    const int lane = t & 63;
    const int q    = lane & 15;
    const int g    = lane >> 4;
    const int k0   = blockIdx.y * KG;
    const long nbase = (long)blockIdx.x * 64;

    const char* prevb = (const char*)(nodes + prev_off * 64); // x-row n at n*256

    // ---- x fragments (B-operand) + epilogue x values (f32) ----
    uint4 af[4][4];
    float xf[4][4];    // x[n][d], d = wave*16 + g*4 + r
    #pragma unroll
    for (int nb = 0; nb < 4; ++nb) {
        const char* xr = prevb + (nbase + nb * 16 + q) * 256;
        #pragma unroll
        for (int s = 0; s < 4; ++s)
            af[nb][s] = *(const uint4*)(xr + s * 64 + g * 16);
        uint2 v = *(const uint2*)(xr + (wave * 16 + g * 4) * 2);
        xf[nb][0] = bflo(v.x); xf[nb][1] = bfhi(v.x);
        xf[nb][2] = bflo(v.y); xf[nb][3] = bfhi(v.y);
    }

    float yreg[16];
    #pragma unroll
    for (int i = 0; i < 16; ++i) yreg[i] = 0.f;

    char* mybuf = smem + wave * 8192;                 // private 2 x 4KB
    const char* ksrc = VtB + (size_t)k0 * 32768 + wave * 4096;  // own 16 rows

    // ---- prologue: stage k0 into parity-0 ----
    #pragma unroll
    for (int i = 0; i < 4; ++i)
        __builtin_amdgcn_global_load_lds(
            (const unsigned int*)(ksrc + i * 1024 + lane * 16),
            (unsigned int*)(mybuf + i * 1024 + lane * 16), 16, 0, 0);
    asm volatile("s_waitcnt vmcnt(0)" ::: "memory");

    #pragma unroll
    for (int kk = 0; kk < KG; ++kk) {
        const char* rb = mybuf + (kk & 1) * 4096;

        // A-fragments: local row q, swizzled 16B chunk ((s*4+g) ^ q)
        bf16x8 vf[4];
        #pragma unroll
        for (int s = 0; s < 4; ++s)
            vf[s] = *(const bf16x8*)(rb + q * 256 + (((s * 4 + g) ^ q) * 16));

        if (kk + 1 < KG) {  // issue next-k staging into the other parity
            const char* src = ksrc + (size_t)(kk + 1) * 32768;
            char* dst = mybuf + ((kk & 1) ^ 1) * 4096;
            #pragma unroll
            for (int i = 0; i < 4; ++i)
                __builtin_amdgcn_global_load_lds(
                    (const unsigned int*)(src + i * 1024 + lane * 16),
                    (unsigned int*)(dst + i * 1024 + lane * 16), 16, 0, 0);
        }

        f32x4 acc[4];
        #pragma unroll
        for (int nb = 0; nb < 4; ++nb) acc[nb] = (f32x4){0.f, 0.f, 0.f, 0.f};
        #pragma unroll
        for (int s = 0; s < 4; ++s)
            #pragma unroll
            for (int nb = 0; nb < 4; ++nb)
                acc[nb] = __builtin_amdgcn_mfma_f32_16x16x32_bf16(
                    vf[s], *(const bf16x8*)&af[nb][s], acc[nb], 0, 0, 0);

        // in-lane d-contraction (4 d's) + pure-VALU g-reduce
        #pragma unroll
        for (int nb = 0; nb < 4; ++nb) {
            float red = acc[nb][0] * xf[nb][0] + acc[nb][1] * xf[nb][1]
                      + acc[nb][2] * xf[nb][2] + acc[nb][3] * xf[nb][3];
            float v = gsum(red);
            if (g == (kk >> 2)) yreg[nb * 4 + (kk & 3)] = v;
        }

        if (kk + 1 < KG)    // per-wave wait: own 4 loads only (no barrier!)
            asm volatile("s_waitcnt vmcnt(0)" ::: "memory");
    }

    // ---- Wx on wave 0 (combine sums waves -> added once) ----
    if (wave == 0) {
        f32x4 accw[4];
        #pragma unroll
        for (int nb = 0; nb < 4; ++nb) accw[nb] = (f32x4){0.f, 0.f, 0.f, 0.f};
        #pragma unroll
        for (int s = 0; s < 4; ++s) {
            bf16x8 wtf = *(const bf16x8*)((const char*)WT
                           + (k0 + (q & (KG - 1))) * 256 + s * 64 + g * 16);
            #pragma unroll
            for (int nb = 0; nb < 4; ++nb)
                accw[nb] = __builtin_amdgcn_mfma_f32_16x16x32_bf16(
                    wtf, *(const bf16x8*)&af[nb][s], accw[nb], 0, 0, 0);
        }
        #pragma unroll
        for (int nb = 0; nb < 4; ++nb)
            #pragma unroll
            for (int r = 0; r < 4; ++r)
                yreg[nb * 4 + r] += accw[nb][r];
    }

    __syncthreads();   // all waves done with private dbufs -> safe to alias Y

    // ---- write per-wave partials Y[wave][n_local][klocal] ----
    #pragma unroll
    for (int nb = 0; nb < 4; ++nb) {
        float4 tmp = make_float4(yreg[nb * 4], yreg[nb * 4 + 1],
                                 yreg[nb * 4 + 2], yreg[nb * 4 + 3]);
        *(float4*)&Y[(wave * 64 + nb * 16 + q) * 20 + g * 4] = tmp;
    }
    __syncthreads();

    // ---- combine 8 d-eighths, +bias, tanh, store bf16 ----
    constexpr int KQB = KG / 4;              // k-quads per node
    if (t < 64 * KQB) {
        int n  = t / KQB;                    // 0..63
        int kq = t % KQB;
        float a0 = 0.f, a1 = 0.f, a2 = 0.f, a3 = 0.f;
        #pragma unroll
        for (int w = 0; w < 8; ++w) {
            float4 v = *(const float4*)&Y[(w * 64 + n) * 20 + kq * 4];
            a0 += v.x; a1 += v.y; a2 += v.z; a3 += v.w;
        }
        int kb = k0 + kq * 4;
        a0 += bias[kb + 0]; a1 += bias[kb + 1];
        a2 += bias[kb + 2]; a3 += bias[kb + 3];
        unsigned int w0 = (unsigned int)f2bf(tanhf(a0))
                        | ((unsigned int)f2bf(tanhf(a1)) << 16);
        unsigned int w1 = (unsigned int)f2bf(tanhf(a2))
                        | ((unsigned int)f2bf(tanhf(a3)) << 16);
        unsigned short* outp = nodes + out_off * 64;
        *(uint2*)(outp + (nbase + n) * 64 + kb) = make_uint2(w0, w1);
    }
}

// ---------------------------------------------------------------------------
// logits + log_softmax (reads bf16 nodes)
// ---------------------------------------------------------------------------
__global__ __launch_bounds__(256) void out_kernel(
    const unsigned short* __restrict__ nodes, const float* __restrict__ Wout,
    float* __restrict__ out, int total)
{
    int r = blockIdx.x * 256 + threadIdx.x;
    if (r >= total) return;
    const uint4* xp = (const uint4*)(nodes + (size_t)r * 64);
    float acc[5] = {0.f, 0.f, 0.f, 0.f, 0.f};
    #pragma unroll
    for (int u4 = 0; u4 < 8; ++u4) {
        uint4 v = xp[u4];
        unsigned int ws[4] = {v.x, v.y, v.z, v.w};
        #pragma unroll
        for (int j = 0; j < 4; ++j) {
            int h = u4 * 8 + j * 2;
            float x0 = bf2f(ws[j] & 0xffffu);
            float x1 = bf2f(ws[j] >> 16);
            #pragma unroll
            for (int o = 0; o < 5; ++o) {
                acc[o] = fmaf(x0, Wout[h * 5 + o], acc[o]);
                acc[o] = fmaf(x1, Wout[(h + 1) * 5 + o], acc[o]);
            }
        }
    }
    float m = acc[0];
    #pragma unroll
    for (int o = 1; o < 5; ++o) m = fmaxf(m, acc[o]);
    float s = 0.f;
    #pragma unroll
    for (int o = 0; o < 5; ++o) s += expf(acc[o] - m);
    float ls = logf(s);
    #pragma unroll
    for (int o = 0; o < 5; ++o) out[(size_t)r * 5 + o] = acc[o] - m - ls;
}

extern "C" void kernel_launch(void* const* d_in, const int* in_sizes, int n_in,
                              void* d_out, int out_size, void* d_ws, size_t ws_size,
                              hipStream_t stream) {
    const int*   ids   = (const int*)d_in[0];
    const float* embed = (const float*)d_in[1];
    const float* Vt    = (const float*)d_in[2];
    const float* W     = (const float*)d_in[3];
    const float* bias  = (const float*)d_in[4];
    const float* Wout  = (const float*)d_in[5];
    float* out = (float*)d_out;

    char* ws = (char*)d_ws;
    unsigned short* nodes = (unsigned short*)ws;           // 130048*64*2 = 16,646,144 B
    char* VtB = ws + 16646144;                             // 64*32768 = 2,097,152 B
    unsigned short* WT = (unsigned short*)(ws + 18743296); // 16,384 B

    prep_kernel<<<65, 256, 0, stream>>>(Vt, W, VtB, WT);
    gather_kernel<<<2048, 256, 0, stream>>>(ids, embed, nodes);

    (void)hipFuncSetAttribute(reinterpret_cast<const void*>(bil_kernel<16>),
                              hipFuncAttributeMaxDynamicSharedMemorySize, 65536);
    (void)hipFuncSetAttribute(reinterpret_cast<const void*>(bil_kernel<8>),
                              hipFuncAttributeMaxDynamicSharedMemorySize, 65536);
    (void)hipFuncSetAttribute(reinterpret_cast<const void*>(bil_kernel<4>),
                              hipFuncAttributeMaxDynamicSharedMemorySize, 65536);

    const int kgs[6] = {16, 16, 16, 16, 8, 4};
    long off_prev = 0, off_cur = 65536;
    int n = 32;
    for (int lev = 0; lev < 6; ++lev) {
        long M = (long)BB * n;                 // internal nodes this level
        int kg = kgs[lev];
        dim3 grid((unsigned)(M / 64), (unsigned)(64 / kg));
        if (kg == 16)
            bil_kernel<16><<<grid, 512, 65536, stream>>>(nodes, VtB, WT, bias,
                                                         off_prev, off_cur);
        else if (kg == 8)
            bil_kernel<8><<<grid, 512, 65536, stream>>>(nodes, VtB, WT, bias,
                                                        off_prev, off_cur);
        else
            bil_kernel<4><<<grid, 512, 65536, stream>>>(nodes, VtB, WT, bias,
                                                        off_prev, off_cur);
        off_prev = off_cur; off_cur += M; n >>= 1;
    }
    out_kernel<<<(130048 + 255) / 256, 256, 0, stream>>>(nodes, Wout, out, 130048);
}

// Round 13
// 198.428 us; speedup vs baseline: 2.7968x; 2.7968x over previous
//
#include <hip/hip_runtime.h>
#include <hip/hip_bf16.h>

#define BB 1024

typedef __attribute__((ext_vector_type(8))) short bf16x8;   // 8 bf16 = 4 VGPRs
typedef __attribute__((ext_vector_type(4))) float f32x4;    // MFMA C/D

__device__ __forceinline__ float bf2f(unsigned int u) {
    union { unsigned int i; float f; } v; v.i = u << 16; return v.f;
}
__device__ __forceinline__ float bflo(unsigned int w) {
    union { unsigned int i; float f; } v; v.i = w << 16; return v.f;
}
__device__ __forceinline__ float bfhi(unsigned int w) {
    union { unsigned int i; float f; } v; v.i = w & 0xffff0000u; return v.f;
}
__device__ __forceinline__ unsigned short f2bf(float f) {
    union { float f; unsigned int i; } v; v.f = f;
    return (unsigned short)((v.i + 0x7fffu + ((v.i >> 16) & 1u)) >> 16);
}

// all-lane sum over lane-bit4 and lane-bit5 (the 4 g-groups), pure VALU:
// v_permlane16_swap + v_permlane32_swap (gfx950; numerics validated in the
// round-9 passing run). Replaces the ds_swizzle xor16 -> no LDS-pipe use.
__device__ __forceinline__ float gsum(float x) {
    float a0 = x, a1 = x;
    asm("v_permlane16_swap_b32 %0, %1" : "+v"(a0), "+v"(a1));
    float s = a0 + a1;
    float b0 = s, b1 = s;
    asm("v_permlane32_swap_b32 %0, %1" : "+v"(b0), "+v"(b1));
    return b0 + b1;
}

// ---------------------------------------------------------------------------
// prep: blocks 0..63: VtB[k][d][c] = bf16(Vt[k][c][d]); the 16B c-blocks of
//       each 256B d-row are XOR-swizzled (blk ^= d&15) so linear
//       global_load_lds staging + swizzled ds_read_b128 is conflict-free.
//       block 64: WT[k][c] = bf16(W[c][k]).
// ---------------------------------------------------------------------------
__global__ __launch_bounds__(256) void prep_kernel(
    const float* __restrict__ Vt, const float* __restrict__ W,
    char* __restrict__ VtB, unsigned short* __restrict__ WT)
{
    const int t = threadIdx.x;
    const int blk = blockIdx.x;
    if (blk < 64) {
        __shared__ float tile[64][132];
        const float* src = Vt + (size_t)blk * 16384;
        for (int h = 0; h < 2; ++h) {          // c-halves
            __syncthreads();
            for (int i = 0; i < 8; ++i) {      // stage 64c x 128d floats
                int f4 = t + i * 256;
                int cl = f4 >> 5;              // 0..63
                int d4 = (f4 & 31) << 2;
                const float* s4 = src + (size_t)(h * 64 + cl) * 128 + d4;
                float4 v = *(const float4*)s4;
                tile[cl][d4] = v.x; tile[cl][d4 + 1] = v.y;
                tile[cl][d4 + 2] = v.z; tile[cl][d4 + 3] = v.w;
            }
            __syncthreads();
            int d = t >> 1, ch = t & 1;
            for (int cb = h * 8 + ch * 4; cb < h * 8 + ch * 4 + 4; ++cb) {
                int cbl = cb - h * 8;
                unsigned int w[4];
                #pragma unroll
                for (int j = 0; j < 4; ++j) {
                    unsigned int lo = f2bf(tile[cbl * 8 + 2 * j][d]);
                    unsigned int hi = f2bf(tile[cbl * 8 + 2 * j + 1][d]);
                    w[j] = lo | (hi << 16);
                }
                int oblk = cb ^ (d & 15);
                *(uint4*)(VtB + (size_t)blk * 32768 + d * 256 + oblk * 16) =
                    make_uint4(w[0], w[1], w[2], w[3]);
            }
        }
    } else {
        for (int i = 0; i < 32; ++i) {
            int idx = t * 32 + i;
            int k = idx >> 7, c = idx & 127;
            WT[idx] = f2bf(W[c * 64 + k]);
        }
    }
}

// ---------------------------------------------------------------------------
// leaf gather -> bf16 node rows
// ---------------------------------------------------------------------------
__global__ __launch_bounds__(256) void gather_kernel(
    const int* __restrict__ ids, const float* __restrict__ embed,
    unsigned short* __restrict__ nodes)
{
    int e = blockIdx.x * 256 + threadIdx.x;  // 16B chunk, 8 per row
    int row = e >> 3;
    int part = e & 7;
    int id = ids[row];
    const float* src = embed + (size_t)id * 64 + part * 8;
    float4 a = *(const float4*)src;
    float4 b = *(const float4*)(src + 4);
    unsigned int w0 = (unsigned int)f2bf(a.x) | ((unsigned int)f2bf(a.y) << 16);
    unsigned int w1 = (unsigned int)f2bf(a.z) | ((unsigned int)f2bf(a.w) << 16);
    unsigned int w2 = (unsigned int)f2bf(b.x) | ((unsigned int)f2bf(b.y) << 16);
    unsigned int w3 = (unsigned int)f2bf(b.z) | ((unsigned int)f2bf(b.w) << 16);
    *(uint4*)(nodes + (size_t)row * 64 + part * 8) = make_uint4(w0, w1, w2, w3);
}

// ---------------------------------------------------------------------------
// One tree level (EXACT round-8 structure -- the proven-passing one; only
// gsum changed to pure-VALU permlanes). 512 thr = 8 waves =
// (dq = wave>>1: 32-d quarter) x (p = wave&1: n-half). 128 nodes x KG k per
// block. Vt[k] (32KB) staged ONCE per block into a shared LDS double-buffer
// via global_load_lds (all 8 waves cooperate, 4KB each); fragments read
// with XOR-swizzled ds_read_b128. Sync per k: inline vmcnt(0) +
// __syncthreads() (emits full vmcnt/expcnt/lgkmcnt drain before s_barrier
// -- the only DMA handoff pattern that has passed on this kernel; raw
// s_barrier / vmcnt-only variants raced in rounds 10-12). Per k per wave:
// 8 swizzled ds_read_b128 + 32 MFMA C(d,n)=Vt[k](d,c).x(n,c)^T + in-lane
// 8-d contraction + VALU gsum; lane g keeps k = k0+g*4+slot. Wx: dq==0
// waves, one MFMA pass with WT rows. Final: 4-quarter combine via aliased
// LDS Y + bias + tanh.
// ---------------------------------------------------------------------------
template<int KG>
__global__ __launch_bounds__(512, 1) void bil_kernel(
    unsigned short* __restrict__ nodes, const char* __restrict__ VtB,
    const unsigned short* __restrict__ WT, const float* __restrict__ bias,
    long prev_off, long out_off)
{
    extern __shared__ char smem[];           // 65536: 2 x 32KB Vt dbuf
    float* Y = (float*)smem;                 // post-loop alias: [8][64][20]

    const int t    = threadIdx.x;
    const int wave = t >> 6;
    const int lane = t & 63;
    const int q    = lane & 15;
    const int g    = lane >> 4;
    const int p    = wave & 1;               // n-half
    const int dq   = wave >> 1;              // d-quarter
    const int k0   = blockIdx.y * KG;
    const long nbase = (long)blockIdx.x * 128;

    const char* prevb = (const char*)(nodes + prev_off * 64); // x-row n at n*256

    // ---- x fragments (B-operand) + packed epilogue x values ----
    uint4 af[4][4];
    uint2 xfp[4][2];   // bf16 pairs: x[n][d], d = dq*32 + db*16 + g*4 + r
    #pragma unroll
    for (int nb = 0; nb < 4; ++nb) {
        const char* xr = prevb + (nbase + p * 64 + nb * 16 + q) * 256;
        #pragma unroll
        for (int s = 0; s < 4; ++s)
            af[nb][s] = *(const uint4*)(xr + s * 64 + g * 16);
        #pragma unroll
        for (int db = 0; db < 2; ++db)
            xfp[nb][db] = *(const uint2*)(xr + (dq * 32 + db * 16 + g * 4) * 2);
    }

    float yreg[16];
    #pragma unroll
    for (int i = 0; i < 16; ++i) yreg[i] = 0.f;

    // ---- prologue: stage k0 into buffer 0 (each wave 4KB) ----
    {
        const char* src = VtB + (size_t)k0 * 32768 + wave * 4096;
        char* dst = smem + wave * 4096;
        #pragma unroll
        for (int i = 0; i < 4; ++i)
            __builtin_amdgcn_global_load_lds(
                (const unsigned int*)(src + i * 1024 + lane * 16),
                (unsigned int*)(dst + i * 1024 + lane * 16), 16, 0, 0);
    }
    asm volatile("s_waitcnt vmcnt(0)" ::: "memory");
    __syncthreads();

    #pragma unroll
    for (int kk = 0; kk < KG; ++kk) {
        const char* rb = smem + (kk & 1) * 32768;

        if (kk + 1 < KG) {  // stage next k into the other buffer (no wait)
            const char* src = VtB + (size_t)(k0 + kk + 1) * 32768 + wave * 4096;
            char* dst = smem + ((kk & 1) ^ 1) * 32768 + wave * 4096;
            #pragma unroll
            for (int i = 0; i < 4; ++i)
                __builtin_amdgcn_global_load_lds(
                    (const unsigned int*)(src + i * 1024 + lane * 16),
                    (unsigned int*)(dst + i * 1024 + lane * 16), 16, 0, 0);
        }

        float red[4];
        #pragma unroll
        for (int nb = 0; nb < 4; ++nb) red[nb] = 0.f;

        #pragma unroll
        for (int db = 0; db < 2; ++db) {
            // A-fragments (Vt rows d = dq*32 + db*16 + q), swizzled blocks
            bf16x8 vf[4];
            #pragma unroll
            for (int s = 0; s < 4; ++s)
                vf[s] = *(const bf16x8*)(rb + (dq * 32 + db * 16 + q) * 256
                                         + (((s * 4 + g) ^ q) * 16));
            f32x4 acc[4];
            #pragma unroll
            for (int nb = 0; nb < 4; ++nb) acc[nb] = (f32x4){0.f, 0.f, 0.f, 0.f};
            #pragma unroll
            for (int s = 0; s < 4; ++s)
                #pragma unroll
                for (int nb = 0; nb < 4; ++nb)
                    acc[nb] = __builtin_amdgcn_mfma_f32_16x16x32_bf16(
                        vf[s], *(const bf16x8*)&af[nb][s], acc[nb], 0, 0, 0);
            // in-lane d-contraction (4 d's of this db)
            #pragma unroll
            for (int nb = 0; nb < 4; ++nb) {
                uint2 w = xfp[nb][db];
                red[nb] += acc[nb][0] * bflo(w.x) + acc[nb][1] * bfhi(w.x)
                         + acc[nb][2] * bflo(w.y) + acc[nb][3] * bfhi(w.y);
            }
        }

        // pure-VALU g-reduce + lane-select keep
        #pragma unroll
        for (int nb = 0; nb < 4; ++nb) {
            float v = gsum(red[nb]);
            if (g == (kk >> 2)) yreg[nb * 4 + (kk & 3)] = v;
        }

        asm volatile("s_waitcnt vmcnt(0)" ::: "memory");
        __syncthreads();
    }

    // ---- Wx on dq==0 waves (added once per k,n across the block) ----
    if (dq == 0) {
        f32x4 accw[4];
        #pragma unroll
        for (int nb = 0; nb < 4; ++nb) accw[nb] = (f32x4){0.f, 0.f, 0.f, 0.f};
        #pragma unroll
        for (int s = 0; s < 4; ++s) {
            bf16x8 wtf = *(const bf16x8*)((const char*)WT
                           + (k0 + (q & (KG - 1))) * 256 + s * 64 + g * 16);
            #pragma unroll
            for (int nb = 0; nb < 4; ++nb)
                accw[nb] = __builtin_amdgcn_mfma_f32_16x16x32_bf16(
                    wtf, *(const bf16x8*)&af[nb][s], accw[nb], 0, 0, 0);
        }
        // accw row = g*4 + r == yreg slot layout -> direct add
        #pragma unroll
        for (int nb = 0; nb < 4; ++nb)
            #pragma unroll
            for (int r = 0; r < 4; ++r)
                yreg[nb * 4 + r] += accw[nb][r];
    }

    // ---- write per-wave partials Y[wave][n_local][klocal] ----
    #pragma unroll
    for (int nb = 0; nb < 4; ++nb) {
        float4 tmp = make_float4(yreg[nb * 4], yreg[nb * 4 + 1],
                                 yreg[nb * 4 + 2], yreg[nb * 4 + 3]);
        *(float4*)&Y[(wave * 64 + nb * 16 + q) * 20 + g * 4] = tmp;
    }
    __syncthreads();

    // ---- combine 4 d-quarters, +bias, tanh, store bf16 ----
    constexpr int KQB = KG / 4;              // k-quads per node
    if (t < 128 * KQB) {
        int n  = t / KQB;                    // 0..127
        int kq = t % KQB;
        int pp = n >> 6, nl = n & 63;
        float a0 = 0.f, a1 = 0.f, a2 = 0.f, a3 = 0.f;
        #pragma unroll
        for (int d4 = 0; d4 < 4; ++d4) {
            float4 v = *(const float4*)&Y[((d4 * 2 + pp) * 64 + nl) * 20 + kq * 4];
            a0 += v.x; a1 += v.y; a2 += v.z; a3 += v.w;
        }
        int kb = k0 + kq * 4;
        a0 += bias[kb + 0]; a1 += bias[kb + 1];
        a2 += bias[kb + 2]; a3 += bias[kb + 3];
        unsigned int w0 = (unsigned int)f2bf(tanhf(a0))
                        | ((unsigned int)f2bf(tanhf(a1)) << 16);
        unsigned int w1 = (unsigned int)f2bf(tanhf(a2))
                        | ((unsigned int)f2bf(tanhf(a3)) << 16);
        unsigned short* outp = nodes + out_off * 64;
        *(uint2*)(outp + (nbase + n) * 64 + kb) = make_uint2(w0, w1);
    }
}

// ---------------------------------------------------------------------------
// logits + log_softmax (reads bf16 nodes)
// ---------------------------------------------------------------------------
__global__ __launch_bounds__(256) void out_kernel(
    const unsigned short* __restrict__ nodes, const float* __restrict__ Wout,
    float* __restrict__ out, int total)
{
    int r = blockIdx.x * 256 + threadIdx.x;
    if (r >= total) return;
    const uint4* xp = (const uint4*)(nodes + (size_t)r * 64);
    float acc[5] = {0.f, 0.f, 0.f, 0.f, 0.f};
    #pragma unroll
    for (int u4 = 0; u4 < 8; ++u4) {
        uint4 v = xp[u4];
        unsigned int ws[4] = {v.x, v.y, v.z, v.w};
        #pragma unroll
        for (int j = 0; j < 4; ++j) {
            int h = u4 * 8 + j * 2;
            float x0 = bf2f(ws[j] & 0xffffu);
            float x1 = bf2f(ws[j] >> 16);
            #pragma unroll
            for (int o = 0; o < 5; ++o) {
                acc[o] = fmaf(x0, Wout[h * 5 + o], acc[o]);
                acc[o] = fmaf(x1, Wout[(h + 1) * 5 + o], acc[o]);
            }
        }
    }
    float m = acc[0];
    #pragma unroll
    for (int o = 1; o < 5; ++o) m = fmaxf(m, acc[o]);
    float s = 0.f;
    #pragma unroll
    for (int o = 0; o < 5; ++o) s += expf(acc[o] - m);
    float ls = logf(s);
    #pragma unroll
    for (int o = 0; o < 5; ++o) out[(size_t)r * 5 + o] = acc[o] - m - ls;
}

extern "C" void kernel_launch(void* const* d_in, const int* in_sizes, int n_in,
                              void* d_out, int out_size, void* d_ws, size_t ws_size,
                              hipStream_t stream) {
    const int*   ids   = (const int*)d_in[0];
    const float* embed = (const float*)d_in[1];
    const float* Vt    = (const float*)d_in[2];
    const float* W     = (const float*)d_in[3];
    const float* bias  = (const float*)d_in[4];
    const float* Wout  = (const float*)d_in[5];
    float* out = (float*)d_out;

    char* ws = (char*)d_ws;
    unsigned short* nodes = (unsigned short*)ws;           // 130048*64*2 = 16,646,144 B
    char* VtB = ws + 16646144;                             // 64*32768 = 2,097,152 B
    unsigned short* WT = (unsigned short*)(ws + 18743296); // 16,384 B

    prep_kernel<<<65, 256, 0, stream>>>(Vt, W, VtB, WT);
    gather_kernel<<<2048, 256, 0, stream>>>(ids, embed, nodes);

    (void)hipFuncSetAttribute(reinterpret_cast<const void*>(bil_kernel<16>),
                              hipFuncAttributeMaxDynamicSharedMemorySize, 65536);
    (void)hipFuncSetAttribute(reinterpret_cast<const void*>(bil_kernel<8>),
                              hipFuncAttributeMaxDynamicSharedMemorySize, 65536);
    (void)hipFuncSetAttribute(reinterpret_cast<const void*>(bil_kernel<4>),
                              hipFuncAttributeMaxDynamicSharedMemorySize, 65536);

    const int kgs[6] = {16, 16, 16, 8, 4, 4};
    long off_prev = 0, off_cur = 65536;
    int n = 32;
    for (int lev = 0; lev < 6; ++lev) {
        long M = (long)BB * n;                 // internal nodes this level
        int kg = kgs[lev];
        dim3 grid((unsigned)(M / 128), (unsigned)(64 / kg));
        if (kg == 16)
            bil_kernel<16><<<grid, 512, 65536, stream>>>(nodes, VtB, WT, bias,
                                                         off_prev, off_cur);
        else if (kg == 8)
            bil_kernel<8><<<grid, 512, 65536, stream>>>(nodes, VtB, WT, bias,
                                                        off_prev, off_cur);
        else
            bil_kernel<4><<<grid, 512, 65536, stream>>>(nodes, VtB, WT, bias,
                                                        off_prev, off_cur);
        off_prev = off_cur; off_cur += M; n >>= 1;
    }
    out_kernel<<<(130048 + 255) / 256, 256, 0, stream>>>(nodes, Wout, out, 130048);
}